// Round 5
// baseline (108.640 us; speedup 1.0000x reference)
//
#include <hip/hip_runtime.h>
#include <hip/hip_bf16.h>
#include <cstdint>

#define B_   8
#define C_   128
#define H_   64
#define W_   64
#define NPT  9
#define OC   256
#define K_   (C_*NPT)   // 1152
#define HW   (H_*W_)    // 4096
#define MTOT (B_*HW)    // 32768

typedef __attribute__((ext_vector_type(8))) short short8;
typedef __attribute__((ext_vector_type(4))) float f32x4;
typedef __attribute__((ext_vector_type(4))) unsigned int u32x4;
typedef __attribute__((ext_vector_type(2))) unsigned int u32x2;

static __device__ __forceinline__ unsigned short f2bf(float f) {
    union { float f; unsigned u; } a; a.f = f;
    unsigned r = a.u + 0x7fffu + ((a.u >> 16) & 1u);   // RNE
    return (unsigned short)(r >> 16);
}
static __device__ __forceinline__ float bf2f(unsigned short u) {
    union { unsigned u; float f; } a; a.u = ((unsigned)u) << 16;
    return a.f;
}

// ---------------- Kernel A: fp32 offset conv, LDS-staged weights ----------------
__global__ __launch_bounds__(512) void k_offset2(const float* __restrict__ x,
                                                 const float* __restrict__ pw,
                                                 const float* __restrict__ pb,
                                                 float* __restrict__ off) {
    __shared__ __align__(16) float wlds[128 * 180];   // [c][tap][20 pad] = 92160 B
    __shared__ float red[8 * 64 * 19];                // [cg][j][19 pad]  = 38912 B
    int b = blockIdx.x >> 5;
    int i0 = (blockIdx.x & 31) * 2;
    int t = threadIdx.x;

    for (int idx = t; idx < 128 * 9 * 18; idx += 512) {
        int c = idx / 162;
        int r = idx - c * 162;
        int tap = r / 18;
        int o = r - tap * 18;
        wlds[c * 180 + tap * 20 + o] = pw[o * K_ + c * 9 + tap];
    }
    __syncthreads();

    int j = t & 63;
    int cg = t >> 6;
    const float* xb = x + (size_t)b * C_ * HW;
    float acc[2][18];
#pragma unroll
    for (int p = 0; p < 2; ++p)
#pragma unroll
        for (int o = 0; o < 18; ++o) acc[p][o] = 0.f;

    for (int cc = 0; cc < 16; ++cc) {
        int c = cg * 16 + cc;
        const float* xc = xb + (size_t)c * HW;
        float xv[4][3];
#pragma unroll
        for (int q = 0; q < 4; ++q) {
            int row = i0 - 1 + q;
            if (row >= 0 && row < H_) {
                const float* xr = xc + row * W_;
                xv[q][1] = xr[j];
                xv[q][0] = (j > 0)  ? xr[j - 1] : 0.f;
                xv[q][2] = (j < 63) ? xr[j + 1] : 0.f;
            } else {
                xv[q][0] = xv[q][1] = xv[q][2] = 0.f;
            }
        }
        const float* wc = wlds + c * 180;
#pragma unroll
        for (int tap = 0; tap < 9; ++tap) {
            const int kh = tap / 3, kw = tap % 3;
            float w18[20];
            *(f32x4*)(w18 + 0)  = *(const f32x4*)(wc + tap * 20 + 0);
            *(f32x4*)(w18 + 4)  = *(const f32x4*)(wc + tap * 20 + 4);
            *(f32x4*)(w18 + 8)  = *(const f32x4*)(wc + tap * 20 + 8);
            *(f32x4*)(w18 + 12) = *(const f32x4*)(wc + tap * 20 + 12);
            *(f32x4*)(w18 + 16) = *(const f32x4*)(wc + tap * 20 + 16);
#pragma unroll
            for (int p = 0; p < 2; ++p) {
                float xval = xv[p + kh][kw];
#pragma unroll
                for (int o = 0; o < 18; ++o) acc[p][o] += w18[o] * xval;
            }
        }
    }

#pragma unroll
    for (int p = 0; p < 2; ++p) {
        __syncthreads();
#pragma unroll
        for (int o = 0; o < 18; ++o) red[(cg * 64 + j) * 19 + o] = acc[p][o];
        __syncthreads();
        for (int e = t; e < 64 * 18; e += 512) {
            int jj = e / 18, o = e - jj * 18;
            float s = 0.f;
#pragma unroll
            for (int g = 0; g < 8; ++g) s += red[(g * 64 + jj) * 19 + o];
            off[(((size_t)b * 18 + o) * H_ + (i0 + p)) * W_ + jj] = s + pb[o];
        }
    }
}

// ---------------- Kernel W: fold BN scale into bf16 weights, K reordered k = n*128 + c ----------------
__global__ __launch_bounds__(256) void k_prepw(const float* __restrict__ cw,
                                               const float* __restrict__ gam,
                                               const float* __restrict__ bet,
                                               const float* __restrict__ mu,
                                               const float* __restrict__ var,
                                               __hip_bfloat16* __restrict__ wbf,
                                               float* __restrict__ bias) {
    int idx = blockIdx.x * 256 + threadIdx.x;   // output index, 0 .. 294911
    int oc = idx / K_;
    int r = idx - oc * K_;
    int n = r >> 7;            // point index
    int c = r & 127;           // channel
    float sc = gam[oc] * rsqrtf(var[oc] + 1e-5f);
    wbf[idx] = __float2bfloat16(cw[oc * K_ + c * NPT + n] * sc);
    if (blockIdx.x == 0 && threadIdx.x < OC) {
        int o = threadIdx.x;
        float s = gam[o] * rsqrtf(var[o] + 1e-5f);
        bias[o] = bet[o] - mu[o] * s;
    }
}

// ---------------- Kernel G: spatial-major LDS gather -> x_off [px][n*128+c] bf16 ----------------
// Block = (b, row i), 256 threads = (cg 0..3 wave, j 0..63 lane).
// sx layout: byte = (s*64+col)*256 + ((g ^ (col&15))<<4) + (c&7)*2, g = c>>3.
__global__ __launch_bounds__(256) void k_gather(const float* __restrict__ x,
                                                const float* __restrict__ off,
                                                __hip_bfloat16* __restrict__ xoff) {
    __shared__ __align__(16) char sx[5 * 64 * 256];   // 81920 B -> 2 blocks/CU
    int b = blockIdx.x >> 6;
    int i = blockIdx.x & 63;
    int t = threadIdx.x;

    // ---- phase 1: stage rows i-1..i+3 (clamped), channel-contiguous + granule swizzle ----
    const float* xb = x + (size_t)b * C_ * HW;
#pragma unroll 4
    for (int it = 0; it < 40; ++it) {
        int ch = it * 256 + t;          // 10240 float4 chunks
        int c4 = ch & 15;
        int c  = (ch >> 4) & 127;
        int s  = ch >> 11;
        int gr = min(63, max(0, i - 1 + s));
        f32x4 v = *(const f32x4*)(xb + (size_t)c * HW + gr * 64 + c4 * 4);
        int g = c >> 3;
        int sub = (c & 7) * 2;
#pragma unroll
        for (int k2 = 0; k2 < 4; ++k2) {
            int col = c4 * 4 + k2;
            *(unsigned short*)(sx + (s * 64 + col) * 256 + (((g ^ (col & 15)) << 4) + sub)) = f2bf(v[k2]);
        }
    }

    // preload the 18 offsets for this (i, j)
    int j = t & 63;
    int cg = t >> 6;
    float oxv[9], oyv[9];
    const float* ob = off + (((size_t)b * 18) * H_ + i) * W_ + j;
#pragma unroll
    for (int n = 0; n < 9; ++n) {
        oxv[n] = ob[(size_t)n * HW];
        oyv[n] = ob[(size_t)(n + 9) * HW];
    }
    __syncthreads();

    // ---- phase 3: per (j, n): 4 taps x 4 granules of 8 ch via ds_read_b128 ----
    char* outp = (char*)xoff + ((size_t)blockIdx.x * 64 + j) * (K_ * 2) + cg * 64;
    for (int n = 0; n < 9; ++n) {
        float pxf = (float)(i + n / 3) + oxv[n];
        float pyf = (float)(j + n % 3) + oyv[n];
        float fx = floorf(pxf), fy = floorf(pyf);
        int r0 = max(0, min(63, (int)fx));
        int r1 = max(0, min(63, (int)fx + 1));
        int c0 = max(0, min(63, (int)fy));
        int c1 = max(0, min(63, (int)fy + 1));
        float pxc = fminf(fmaxf(pxf, 0.f), 63.f);
        float pyc = fminf(fmaxf(pyf, 0.f), 63.f);
        float ax = 1.f + ((float)r0 - pxc);
        float bx = 1.f - ((float)r1 - pxc);
        float ay = 1.f + ((float)c0 - pyc);
        float by = 1.f - ((float)c1 - pyc);
        float w00 = ax * ay, w11 = bx * by, w01 = ax * by, w10 = bx * ay;
        int s0 = max(0, min(4, r0 - (i - 1)));
        int s1 = max(0, min(4, r1 - (i - 1)));
        const char* b00 = sx + (s0 * 64 + c0) * 256;
        const char* b11 = sx + (s1 * 64 + c1) * 256;
        const char* b01 = sx + (s0 * 64 + c1) * 256;
        const char* b10 = sx + (s1 * 64 + c0) * 256;
        int x0m = (c0 & 15) << 4, x1m = (c1 & 15) << 4;
#pragma unroll
        for (int u = 0; u < 4; ++u) {
            int gb = (cg * 4 + u) << 4;
            short8 t00 = *(const short8*)(b00 + (gb ^ x0m));
            short8 t11 = *(const short8*)(b11 + (gb ^ x1m));
            short8 t01 = *(const short8*)(b01 + (gb ^ x1m));
            short8 t10 = *(const short8*)(b10 + (gb ^ x0m));
            u32x4 pk;
#pragma unroll
            for (int p2 = 0; p2 < 4; ++p2) {
                unsigned short rr[2];
#pragma unroll
                for (int e = 0; e < 2; ++e) {
                    int ei = p2 * 2 + e;
                    float v = w00 * bf2f((unsigned short)t00[ei])
                            + w11 * bf2f((unsigned short)t11[ei])
                            + w01 * bf2f((unsigned short)t01[ei])
                            + w10 * bf2f((unsigned short)t10[ei]);
                    rr[e] = f2bf(v);
                }
                pk[p2] = (uint32_t)rr[0] | ((uint32_t)rr[1] << 16);
            }
            *(u32x4*)(outp + n * 256 + u * 16) = pk;
        }
    }
}

// ---------------- Kernel M: bf16 MFMA GEMM, BN=256 (A read once) ----------------
#define GBM 128
#define GBN 256
#define GBK 64
#define NT_G (K_ / GBK)   // 18

__global__ __launch_bounds__(512) void k_gemm(const __hip_bfloat16* __restrict__ xoff,
                                              const __hip_bfloat16* __restrict__ wbf,
                                              const float* __restrict__ bias,
                                              float* __restrict__ out) {
    __shared__ __align__(16) char smem[2 * (16384 + 32768)];  // 96 KiB
    int tid = threadIdx.x;
    int mt = blockIdx.x;
    const char* Ab = (const char*)xoff + (size_t)mt * GBM * (K_ * 2);
    const char* Bb = (const char*)wbf;

    auto stage = [&](int buf, int kt) {
        const int winByte = kt * (GBK * 2);
        char* base = smem + buf * 49152;
#pragma unroll
        for (int q = 0; q < 2; ++q) {       // A: 1024 chunks
            int ch = q * 512 + tid;
            int row = ch >> 3, slot = ch & 7;
            int srcoff = row * (K_ * 2) + winByte + ((slot * 16) ^ ((row & 7) << 4));
            __builtin_amdgcn_global_load_lds(
                (const __attribute__((address_space(1))) uint32_t*)(Ab + srcoff),
                (__attribute__((address_space(3))) uint32_t*)(base + ch * 16), 16, 0, 0);
        }
#pragma unroll
        for (int q = 0; q < 4; ++q) {       // B: 2048 chunks
            int ch = q * 512 + tid;
            int row = ch >> 3, slot = ch & 7;
            int srcoff = row * (K_ * 2) + winByte + ((slot * 16) ^ ((row & 7) << 4));
            __builtin_amdgcn_global_load_lds(
                (const __attribute__((address_space(1))) uint32_t*)(Bb + srcoff),
                (__attribute__((address_space(3))) uint32_t*)(base + 16384 + ch * 16), 16, 0, 0);
        }
    };

    int wv = tid >> 6, lane = tid & 63;
    int wr = wv >> 2, wc = wv & 3;          // wave: 64 px x 64 oc of the 128x256 tile
    int lrow = lane & 15, lg = lane >> 4;

    f32x4 zero = {0.f, 0.f, 0.f, 0.f};
    f32x4 acc[4][4];
#pragma unroll
    for (int m = 0; m < 4; ++m)
#pragma unroll
        for (int n = 0; n < 4; ++n) acc[m][n] = zero;

    stage(0, 0);
    for (int kt = 0; kt < NT_G; ++kt) {
        if (kt + 1 < NT_G) stage((kt + 1) & 1, kt + 1);
        __syncthreads();
        const char* sa = smem + (kt & 1) * 49152;
        const char* sb = sa + 16384;
#pragma unroll
        for (int kk = 0; kk < 2; ++kk) {
            short8 afr[4], bfr[4];
#pragma unroll
            for (int m = 0; m < 4; ++m) {
                int row = wr * 64 + m * 16 + lrow;
                int byt = kk * 64 + lg * 16;
                afr[m] = *(const short8*)(sa + row * 128 + (byt ^ ((row & 7) << 4)));
            }
#pragma unroll
            for (int n = 0; n < 4; ++n) {
                int row = wc * 64 + n * 16 + lrow;
                int byt = kk * 64 + lg * 16;
                bfr[n] = *(const short8*)(sb + row * 128 + (byt ^ ((row & 7) << 4)));
            }
#pragma unroll
            for (int m = 0; m < 4; ++m)
#pragma unroll
                for (int n = 0; n < 4; ++n)
                    acc[m][n] = __builtin_amdgcn_mfma_f32_16x16x32_bf16(afr[m], bfr[n], acc[m][n], 0, 0, 0);
        }
        __syncthreads();
    }

#pragma unroll
    for (int n = 0; n < 4; ++n) {
        int oc = wc * 64 + n * 16 + lrow;
        float bs = bias[oc];
#pragma unroll
        for (int m = 0; m < 4; ++m) {
            int pxb = mt * GBM + wr * 64 + m * 16 + lg * 4;
#pragma unroll
            for (int r = 0; r < 4; ++r) {
                int px = pxb + r;
                float v = acc[m][n][r] + bs;
                float sv = v / (1.f + __expf(-v));
                out[((size_t)(px >> 12) * OC + oc) * HW + (px & 4095)] = sv;
            }
        }
    }
}

extern "C" void kernel_launch(void* const* d_in, const int* in_sizes, int n_in,
                              void* d_out, int out_size, void* d_ws, size_t ws_size,
                              hipStream_t stream) {
    const float* x   = (const float*)d_in[0];
    const float* pw  = (const float*)d_in[1];
    const float* pb  = (const float*)d_in[2];
    const float* cw  = (const float*)d_in[3];
    const float* gam = (const float*)d_in[4];
    const float* bet = (const float*)d_in[5];
    const float* mu  = (const float*)d_in[6];
    const float* var = (const float*)d_in[7];
    float* out = (float*)d_out;

    char* ws = (char*)d_ws;
    float* off           = (float*)ws;                           // 2,359,296 B
    __hip_bfloat16* wbf  = (__hip_bfloat16*)(ws + 2359296);      //   589,824 B
    float* bias          = (float*)(ws + 2949120);               //     1,024 B
    __hip_bfloat16* xoff = (__hip_bfloat16*)(ws + 2950144);      // 75,497,472 B

    hipLaunchKernelGGL(k_offset2, dim3(256),  dim3(512), 0, stream, x, pw, pb, off);
    hipLaunchKernelGGL(k_prepw,   dim3(1152), dim3(256), 0, stream, cw, gam, bet, mu, var, wbf, bias);
    hipLaunchKernelGGL(k_gather,  dim3(512),  dim3(256), 0, stream, x, off, xoff);
    hipLaunchKernelGGL(k_gemm,    dim3(256),  dim3(512), 0, stream, xoff, wbf, bias, out);
}